// Round 1
// baseline (2246.766 us; speedup 1.0000x reference)
//
#include <hip/hip_runtime.h>
#include <hip/hip_bf16.h>
#include <math.h>

// Problem constants (fixed by the reference)
#define B_TOK 8192
#define IN_DIM 4096
#define HID 2048
#define NE 64
#define TOPK 8

// ---------------------------------------------------------------------------
// GEMM1: h = relu(x @ W1 + b1)   [8192,4096] x [4096,2048]
// fp32 vector-ALU GEMM (no fp32 MFMA on CDNA4). 128x128 tile, BK=16,
// 256 threads, 8x8 register micro-tile per thread.
// ---------------------------------------------------------------------------
#define G1_BM 128
#define G1_BN 128
#define G1_BK 16

__global__ __launch_bounds__(256) void k_gemm1(
    const float* __restrict__ x, const float* __restrict__ W1,
    const float* __restrict__ b1, float* __restrict__ h) {
  __shared__ float As[G1_BK][G1_BM + 4];  // transposed A tile, +4 pad (16B-aligned)
  __shared__ float Bs[G1_BK][G1_BN + 4];
  const int tid = threadIdx.x;
  const int row0 = blockIdx.y * G1_BM;
  const int col0 = blockIdx.x * G1_BN;
  const int tr = (tid >> 4) << 3;  // 0..120, output row offset in tile
  const int tc = (tid & 15) << 3;  // 0..120, output col offset in tile

  float acc[8][8];
#pragma unroll
  for (int i = 0; i < 8; ++i)
#pragma unroll
    for (int j = 0; j < 8; ++j) acc[i][j] = 0.f;

  for (int k0 = 0; k0 < IN_DIM; k0 += G1_BK) {
    // ---- stage A (128 rows x 16 k, transposed into LDS) and B (16 x 128) ----
#pragma unroll
    for (int i = 0; i < 2; ++i) {
      const int idx = tid + (i << 8);          // 0..511
      const int ar = idx >> 2;                 // 0..127
      const int ak = (idx & 3) << 2;           // 0,4,8,12
      const float4 a =
          *(const float4*)&x[(size_t)(row0 + ar) * IN_DIM + k0 + ak];
      As[ak + 0][ar] = a.x;
      As[ak + 1][ar] = a.y;
      As[ak + 2][ar] = a.z;
      As[ak + 3][ar] = a.w;
      const int bk = idx >> 5;                 // 0..15
      const int bc = (idx & 31) << 2;          // 0..124
      *(float4*)&Bs[bk][bc] =
          *(const float4*)&W1[(size_t)(k0 + bk) * HID + col0 + bc];
    }
    __syncthreads();
    // ---- inner product over the K-tile ----
#pragma unroll
    for (int kk = 0; kk < G1_BK; ++kk) {
      const float4 a0 = *(const float4*)&As[kk][tr];
      const float4 a1 = *(const float4*)&As[kk][tr + 4];
      const float4 b0 = *(const float4*)&Bs[kk][tc];
      const float4 b1v = *(const float4*)&Bs[kk][tc + 4];
      const float av[8] = {a0.x, a0.y, a0.z, a0.w, a1.x, a1.y, a1.z, a1.w};
      const float bv[8] = {b0.x, b0.y, b0.z, b0.w, b1v.x, b1v.y, b1v.z, b1v.w};
#pragma unroll
      for (int i = 0; i < 8; ++i)
#pragma unroll
        for (int j = 0; j < 8; ++j) acc[i][j] = fmaf(av[i], bv[j], acc[i][j]);
    }
    __syncthreads();
  }
  // ---- epilogue: bias + relu + coalesced float4 store ----
#pragma unroll
  for (int i = 0; i < 8; ++i) {
    float* hout = &h[(size_t)(row0 + tr + i) * HID + col0 + tc];
#pragma unroll
    for (int j = 0; j < 8; j += 4) {
      float4 o;
      o.x = fmaxf(acc[i][j + 0] + b1[col0 + tc + j + 0], 0.f);
      o.y = fmaxf(acc[i][j + 1] + b1[col0 + tc + j + 1], 0.f);
      o.z = fmaxf(acc[i][j + 2] + b1[col0 + tc + j + 2], 0.f);
      o.w = fmaxf(acc[i][j + 3] + b1[col0 + tc + j + 3], 0.f);
      *(float4*)&hout[j] = o;
    }
  }
}

// ---------------------------------------------------------------------------
// noise_logit = x @ noise_weight   [8192,4096] x [4096,64]
// 8 rows/block, 512 threads (8 waves; wave = one row, lane = expert col).
// x staged in LDS in 512-wide K chunks; noise_weight streamed (L2-resident).
// ---------------------------------------------------------------------------
__global__ __launch_bounds__(512) void k_noise(
    const float* __restrict__ x, const float* __restrict__ nw,
    float* __restrict__ nlogit) {
  __shared__ float xs[8][512];
  const int tid = threadIdx.x;
  const int row0 = blockIdx.x << 3;
  const int lr = tid >> 6;
  const int col = tid & 63;
  float acc = 0.f;
  for (int k0 = 0; k0 < IN_DIM; k0 += 512) {
    __syncthreads();  // protect xs against previous-iteration readers
#pragma unroll
    for (int i = 0; i < 2; ++i) {
      const int idx = tid + (i << 9);   // 0..1023
      const int r = idx >> 7;           // 0..7
      const int c = (idx & 127) << 2;   // 0..508
      *(float4*)&xs[r][c] =
          *(const float4*)&x[(size_t)(row0 + r) * IN_DIM + k0 + c];
    }
    __syncthreads();
#pragma unroll 8
    for (int kk = 0; kk < 512; ++kk)
      acc = fmaf(xs[lr][kk], nw[(k0 + kk) * NE + col], acc);
  }
  nlogit[(row0 + lr) * NE + col] = acc;
}

// ---------------------------------------------------------------------------
// logits = h @ W2 + b2 + noise_eps * nlogit ; ew = softmax(logits, axis=-1);
// per-block column partial sums (deterministic, no atomics).
// 8 rows/block, 512 threads; wave = one row, lane = expert col.
// ---------------------------------------------------------------------------
__global__ __launch_bounds__(512) void k_gemm2_softmax(
    const float* __restrict__ h, const float* __restrict__ W2,
    const float* __restrict__ b2, const float* __restrict__ noise_eps,
    const float* __restrict__ nlogit, float* __restrict__ ew,
    float* __restrict__ partials) {
  __shared__ float hs[8][HID];     // 64 KiB
  __shared__ float psum[8][NE];
  const int tid = threadIdx.x;
  const int row0 = blockIdx.x << 3;
  {
    const float4* src = (const float4*)&h[(size_t)row0 * HID];
    float4* dst = (float4*)&hs[0][0];
    for (int i = tid; i < (8 * HID) / 4; i += 512) dst[i] = src[i];
  }
  __syncthreads();
  const int lr = tid >> 6;
  const int col = tid & 63;
  const float* hrow = &hs[lr][0];
  float acc = 0.f;
#pragma unroll 8
  for (int k = 0; k < HID; ++k) acc = fmaf(hrow[k], W2[k * NE + col], acc);
  const int row = row0 + lr;
  const float logit =
      acc + b2[col] + noise_eps[row * NE + col] * nlogit[row * NE + col];
  // wave-wide softmax across the 64 experts (lane = expert)
  float m = logit;
#pragma unroll
  for (int o = 32; o > 0; o >>= 1) m = fmaxf(m, __shfl_xor(m, o));
  const float e = __expf(logit - m);
  float s = e;
#pragma unroll
  for (int o = 32; o > 0; o >>= 1) s += __shfl_xor(s, o);
  const float p = e / s;
  ew[row * NE + col] = p;
  psum[lr][col] = p;
  __syncthreads();
  if (tid < NE) {
    float t = 0.f;
#pragma unroll
    for (int r = 0; r < 8; ++r) t += psum[r][tid];
    partials[blockIdx.x * NE + tid] = t;
  }
}

// ---------------------------------------------------------------------------
// total = total_prev + sum(partials); mask = (total - mean(total) > 0) ? 0 : 1
// Single block, 64 threads, fixed-order reduction (deterministic).
// ---------------------------------------------------------------------------
__global__ void k_mask(const float* __restrict__ partials,
                       const float* __restrict__ total_prev,
                       float* __restrict__ maskbuf, int nblocks) {
  const int e = threadIdx.x;  // 0..63
  float t = total_prev[e];
  for (int b = 0; b < nblocks; ++b) t += partials[b * NE + e];
  float s = t;
#pragma unroll
  for (int o = 32; o > 0; o >>= 1) s += __shfl_xor(s, o);
  const float mean = s * (1.f / 64.f);
  maskbuf[e] = (t - mean > 0.f) ? 0.f : 1.f;
}

// ---------------------------------------------------------------------------
// Final: ew *= mask; keep top-8 per row (ties keep larger index, matching
// jax top_k(-ew) drop order); softmax over kept values; others -> 0.
// Wave = one row, lane = expert.
// ---------------------------------------------------------------------------
__global__ __launch_bounds__(256) void k_final(
    const float* __restrict__ ew, const float* __restrict__ maskbuf,
    float* __restrict__ out) {
  const int tid = threadIdx.x;
  const int lane = tid & 63;
  const int row = (blockIdx.x << 2) + (tid >> 6);
  const float v = ew[row * NE + lane] * maskbuf[lane];
  // rank = number of strictly-preferred experts (value desc, index desc on tie)
  int rank = 0;
#pragma unroll
  for (int j = 0; j < 64; ++j) {
    const float vj = __shfl(v, j);
    rank += (vj > v) || (vj == v && j > lane);
  }
  const bool keep = rank < TOPK;
  float m = keep ? v : -INFINITY;
#pragma unroll
  for (int o = 32; o > 0; o >>= 1) m = fmaxf(m, __shfl_xor(m, o));
  const float e = keep ? __expf(v - m) : 0.f;
  float s = e;
#pragma unroll
  for (int o = 32; o > 0; o >>= 1) s += __shfl_xor(s, o);
  out[row * NE + lane] = e / s;
}

// ---------------------------------------------------------------------------
extern "C" void kernel_launch(void* const* d_in, const int* in_sizes, int n_in,
                              void* d_out, int out_size, void* d_ws,
                              size_t ws_size, hipStream_t stream) {
  const float* x = (const float*)d_in[0];        // [8192,4096]
  const float* W1 = (const float*)d_in[1];       // [4096,2048]
  const float* b1 = (const float*)d_in[2];       // [2048]
  const float* W2 = (const float*)d_in[3];       // [2048,64]
  const float* b2 = (const float*)d_in[4];       // [64]
  const float* nw = (const float*)d_in[5];       // [4096,64]
  const float* neps = (const float*)d_in[6];     // [8192,64]
  const float* tprev = (const float*)d_in[7];    // [64]
  float* out = (float*)d_out;                    // [8192,64]

  // Workspace layout (~68.5 MB total)
  float* h = (float*)d_ws;                          // 8192*2048 = 64 MB
  float* nlogit = h + (size_t)B_TOK * HID;          // 8192*64   = 2 MB
  float* ewbuf = nlogit + (size_t)B_TOK * NE;       // 8192*64   = 2 MB
  float* partials = ewbuf + (size_t)B_TOK * NE;     // 1024*64   = 256 KB
  float* maskbuf = partials + (B_TOK / 8) * NE;     // 64

  dim3 g1(HID / G1_BN, B_TOK / G1_BM);  // 16 x 64 = 1024 blocks
  k_gemm1<<<g1, 256, 0, stream>>>(x, W1, b1, h);
  k_noise<<<B_TOK / 8, 512, 0, stream>>>(x, nw, nlogit);
  k_gemm2_softmax<<<B_TOK / 8, 512, 0, stream>>>(h, W2, b2, neps, nlogit,
                                                 ewbuf, partials);
  k_mask<<<1, 64, 0, stream>>>(partials, tprev, maskbuf, B_TOK / 8);
  k_final<<<B_TOK / 4, 256, 0, stream>>>(ewbuf, maskbuf, out);
}

// Round 3
// 1093.831 us; speedup vs baseline: 2.0540x; 2.0540x over previous
//
#include <hip/hip_runtime.h>
#include <hip/hip_bf16.h>
#include <math.h>

// Problem constants (fixed by the reference)
#define B_TOK 8192
#define IN_DIM 4096
#define HID 2048
#define NE 64
#define TOPK 8

typedef __attribute__((ext_vector_type(8))) _Float16 f16x8;
typedef __attribute__((ext_vector_type(4))) float f32x4;

// ---------------------------------------------------------------------------
// GEMM1: h = relu(x @ W1 + b1) via split-precision fp16 MFMA.
// x = x_hi + x_lo (fp16 RNE + fp16 of exact fp32 residual); same for W1.
// acc = x_hi*W_hi + x_hi*W_lo + x_lo*W_hi ; dropped lo*lo term ~2^-24 rel
// => full fp32-level accuracy (bf16x3 at 2^-16 caused top-8 boundary flips).
// 128x128 tile, BK=32, 256 threads = 4 waves (2x2), 4x4 16x16x32 frags/wave.
// LDS XOR-swizzled (slot g ^ ((row>>1)&3)) -> 2-way conflicts (free, m136).
// ---------------------------------------------------------------------------
#define BM 128
#define BN 128
#define BK 32

__global__ __launch_bounds__(256) void k_gemm1_mfma(
    const float* __restrict__ x, const float* __restrict__ W1,
    const float* __restrict__ b1, float* __restrict__ h) {
  __shared__ _Float16 AsH[BM * BK];  // [row][k] fp16-hi, 8 KiB
  __shared__ _Float16 AsL[BM * BK];
  __shared__ _Float16 BsH[BN * BK];  // [n][k] fp16-hi (B transposed)
  __shared__ _Float16 BsL[BN * BK];

  const int tid = threadIdx.x;
  const int lane = tid & 63;
  const int w = tid >> 6;
  const int wr = (w >> 1) << 6;  // wave row offset (0/64)
  const int wc = (w & 1) << 6;   // wave col offset (0/64)
  const int row0 = blockIdx.y * BM;
  const int col0 = blockIdx.x * BN;

  // MFMA fragment addressing (loop-invariant):
  // A-frag: A[l&15][(l>>4)*8 + j]; B-frag: B[(l>>4)*8 + j][l&15]
  const int fr = lane & 15;
  const int kg = lane >> 4;
  int aoff[4], boff[4];
#pragma unroll
  for (int m = 0; m < 4; ++m) {
    const int r = wr + m * 16 + fr;
    aoff[m] = r * BK + ((kg ^ ((r >> 1) & 3)) << 3);
  }
#pragma unroll
  for (int n = 0; n < 4; ++n) {
    const int c = wc + n * 16 + fr;
    boff[n] = c * BK + ((kg ^ ((c >> 1) & 3)) << 3);
  }

  f32x4 acc[4][4];
  const f32x4 zero = {0.f, 0.f, 0.f, 0.f};
#pragma unroll
  for (int m = 0; m < 4; ++m)
#pragma unroll
    for (int n = 0; n < 4; ++n) acc[m][n] = zero;

  for (int k0 = 0; k0 < IN_DIM; k0 += BK) {
    __syncthreads();  // prev-iteration readers done before overwrite
    // ---- stage A: 128 rows x 32 k; thread handles 2 chunks of 8 k ----
#pragma unroll
    for (int i = 0; i < 2; ++i) {
      const int ar = (tid >> 2) + i * 64;  // 0..127
      const int g = tid & 3;               // k8 group 0..3
      const float* src = &x[(size_t)(row0 + ar) * IN_DIM + k0 + (g << 3)];
      const float4 f0 = *(const float4*)src;
      const float4 f1 = *(const float4*)(src + 4);
      const float fv[8] = {f0.x, f0.y, f0.z, f0.w, f1.x, f1.y, f1.z, f1.w};
      f16x8 vh, vl;
#pragma unroll
      for (int j = 0; j < 8; ++j) {
        const _Float16 hi = (_Float16)fv[j];        // RNE
        const float res = fv[j] - (float)hi;        // exact in fp32
        vh[j] = hi;
        vl[j] = (_Float16)res;
      }
      const int off = ar * BK + (((g ^ ((ar >> 1) & 3))) << 3);
      *(f16x8*)&AsH[off] = vh;
      *(f16x8*)&AsL[off] = vl;
    }
    // ---- stage B: 32 k x 128 n, transposed to [n][k] during write.
    // thread owns (n = tid&127, k = (tid>>7)*16 .. +15); k-strided loads are
    // lane-coalesced (consecutive n across lanes). ----
    {
      const int n = tid & 127;
      const int k16 = (tid >> 7) << 4;  // 0 or 16
      const float* src = &W1[(size_t)(k0 + k16) * HID + col0 + n];
      float fv[16];
#pragma unroll
      for (int j = 0; j < 16; ++j) fv[j] = src[(size_t)j * HID];
      f16x8 vh0, vl0, vh1, vl1;
#pragma unroll
      for (int j = 0; j < 8; ++j) {
        _Float16 hi = (_Float16)fv[j];
        float res = fv[j] - (float)hi;
        vh0[j] = hi;
        vl0[j] = (_Float16)res;
        hi = (_Float16)fv[j + 8];
        res = fv[j + 8] - (float)hi;
        vh1[j] = hi;
        vl1[j] = (_Float16)res;
      }
      const int g0 = k16 >> 3;  // k8 group of first 8 (0 or 2)
      const int sw = (n >> 1) & 3;
      *(f16x8*)&BsH[n * BK + ((g0 ^ sw) << 3)] = vh0;
      *(f16x8*)&BsL[n * BK + ((g0 ^ sw) << 3)] = vl0;
      *(f16x8*)&BsH[n * BK + (((g0 + 1) ^ sw) << 3)] = vh1;
      *(f16x8*)&BsL[n * BK + (((g0 + 1) ^ sw) << 3)] = vl1;
    }
    __syncthreads();
    // ---- fragments + 48 MFMA (hi*hi, hi*lo, lo*hi) ----
    f16x8 aH[4], bH[4], bL[4], aL[4];
#pragma unroll
    for (int m = 0; m < 4; ++m) aH[m] = *(const f16x8*)&AsH[aoff[m]];
#pragma unroll
    for (int n = 0; n < 4; ++n) bH[n] = *(const f16x8*)&BsH[boff[n]];
#pragma unroll
    for (int m = 0; m < 4; ++m)
#pragma unroll
      for (int n = 0; n < 4; ++n)
        acc[m][n] = __builtin_amdgcn_mfma_f32_16x16x32_f16(aH[m], bH[n],
                                                           acc[m][n], 0, 0, 0);
#pragma unroll
    for (int n = 0; n < 4; ++n) bL[n] = *(const f16x8*)&BsL[boff[n]];
#pragma unroll
    for (int m = 0; m < 4; ++m)
#pragma unroll
      for (int n = 0; n < 4; ++n)
        acc[m][n] = __builtin_amdgcn_mfma_f32_16x16x32_f16(aH[m], bL[n],
                                                           acc[m][n], 0, 0, 0);
#pragma unroll
    for (int m = 0; m < 4; ++m) aL[m] = *(const f16x8*)&AsL[aoff[m]];
#pragma unroll
    for (int m = 0; m < 4; ++m)
#pragma unroll
      for (int n = 0; n < 4; ++n)
        acc[m][n] = __builtin_amdgcn_mfma_f32_16x16x32_f16(aL[m], bH[n],
                                                           acc[m][n], 0, 0, 0);
  }
  // ---- epilogue: bias + relu. C/D: row=(l>>4)*4+j, col=l&15 (m89-verified)
  const int crow = (lane >> 4) << 2;
  const int ccol = lane & 15;
#pragma unroll
  for (int n = 0; n < 4; ++n) {
    const int gc = col0 + wc + n * 16 + ccol;
    const float bias = b1[gc];
#pragma unroll
    for (int m = 0; m < 4; ++m) {
      const int gr = row0 + wr + m * 16 + crow;
#pragma unroll
      for (int j = 0; j < 4; ++j)
        h[(size_t)(gr + j) * HID + gc] = fmaxf(acc[m][n][j] + bias, 0.f);
    }
  }
}

// ---------------------------------------------------------------------------
// noise_logit = x @ noise_weight   [8192,4096] x [4096,64]   (unchanged)
// ---------------------------------------------------------------------------
__global__ __launch_bounds__(512) void k_noise(
    const float* __restrict__ x, const float* __restrict__ nw,
    float* __restrict__ nlogit) {
  __shared__ float xs[8][512];
  const int tid = threadIdx.x;
  const int row0 = blockIdx.x << 3;
  const int lr = tid >> 6;
  const int col = tid & 63;
  float acc = 0.f;
  for (int k0 = 0; k0 < IN_DIM; k0 += 512) {
    __syncthreads();
#pragma unroll
    for (int i = 0; i < 2; ++i) {
      const int idx = tid + (i << 9);
      const int r = idx >> 7;
      const int c = (idx & 127) << 2;
      *(float4*)&xs[r][c] =
          *(const float4*)&x[(size_t)(row0 + r) * IN_DIM + k0 + c];
    }
    __syncthreads();
#pragma unroll 8
    for (int kk = 0; kk < 512; ++kk)
      acc = fmaf(xs[lr][kk], nw[(k0 + kk) * NE + col], acc);
  }
  nlogit[(row0 + lr) * NE + col] = acc;
}

// ---------------------------------------------------------------------------
// logits = h @ W2 + b2 + noise_eps * nlogit ; ew = softmax(logits);
// per-block column partial sums (deterministic).                (unchanged)
// ---------------------------------------------------------------------------
__global__ __launch_bounds__(512) void k_gemm2_softmax(
    const float* __restrict__ h, const float* __restrict__ W2,
    const float* __restrict__ b2, const float* __restrict__ noise_eps,
    const float* __restrict__ nlogit, float* __restrict__ ew,
    float* __restrict__ partials) {
  __shared__ float hs[8][HID];
  __shared__ float psum[8][NE];
  const int tid = threadIdx.x;
  const int row0 = blockIdx.x << 3;
  {
    const float4* src = (const float4*)&h[(size_t)row0 * HID];
    float4* dst = (float4*)&hs[0][0];
    for (int i = tid; i < (8 * HID) / 4; i += 512) dst[i] = src[i];
  }
  __syncthreads();
  const int lr = tid >> 6;
  const int col = tid & 63;
  const float* hrow = &hs[lr][0];
  float acc = 0.f;
#pragma unroll 8
  for (int k = 0; k < HID; ++k) acc = fmaf(hrow[k], W2[k * NE + col], acc);
  const int row = row0 + lr;
  const float logit =
      acc + b2[col] + noise_eps[row * NE + col] * nlogit[row * NE + col];
  float m = logit;
#pragma unroll
  for (int o = 32; o > 0; o >>= 1) m = fmaxf(m, __shfl_xor(m, o));
  const float e = __expf(logit - m);
  float s = e;
#pragma unroll
  for (int o = 32; o > 0; o >>= 1) s += __shfl_xor(s, o);
  const float p = e / s;
  ew[row * NE + col] = p;
  psum[lr][col] = p;
  __syncthreads();
  if (tid < NE) {
    float t = 0.f;
#pragma unroll
    for (int r = 0; r < 8; ++r) t += psum[r][tid];
    partials[blockIdx.x * NE + tid] = t;
  }
}

// ---------------------------------------------------------------------------
// mask from running totals (single block, deterministic)       (unchanged)
// ---------------------------------------------------------------------------
__global__ void k_mask(const float* __restrict__ partials,
                       const float* __restrict__ total_prev,
                       float* __restrict__ maskbuf, int nblocks) {
  const int e = threadIdx.x;
  float t = total_prev[e];
  for (int b = 0; b < nblocks; ++b) t += partials[b * NE + e];
  float s = t;
#pragma unroll
  for (int o = 32; o > 0; o >>= 1) s += __shfl_xor(s, o);
  const float mean = s * (1.f / 64.f);
  maskbuf[e] = (t - mean > 0.f) ? 0.f : 1.f;
}

// ---------------------------------------------------------------------------
// mask + top-8 (ties keep larger index) + renormalizing softmax (unchanged)
// ---------------------------------------------------------------------------
__global__ __launch_bounds__(256) void k_final(
    const float* __restrict__ ew, const float* __restrict__ maskbuf,
    float* __restrict__ out) {
  const int tid = threadIdx.x;
  const int lane = tid & 63;
  const int row = (blockIdx.x << 2) + (tid >> 6);
  const float v = ew[row * NE + lane] * maskbuf[lane];
  int rank = 0;
#pragma unroll
  for (int j = 0; j < 64; ++j) {
    const float vj = __shfl(v, j);
    rank += (vj > v) || (vj == v && j > lane);
  }
  const bool keep = rank < TOPK;
  float m = keep ? v : -INFINITY;
#pragma unroll
  for (int o = 32; o > 0; o >>= 1) m = fmaxf(m, __shfl_xor(m, o));
  const float e = keep ? __expf(v - m) : 0.f;
  float s = e;
#pragma unroll
  for (int o = 32; o > 0; o >>= 1) s += __shfl_xor(s, o);
  out[row * NE + lane] = e / s;
}

// ---------------------------------------------------------------------------
extern "C" void kernel_launch(void* const* d_in, const int* in_sizes, int n_in,
                              void* d_out, int out_size, void* d_ws,
                              size_t ws_size, hipStream_t stream) {
  const float* x = (const float*)d_in[0];
  const float* W1 = (const float*)d_in[1];
  const float* b1 = (const float*)d_in[2];
  const float* W2 = (const float*)d_in[3];
  const float* b2 = (const float*)d_in[4];
  const float* nw = (const float*)d_in[5];
  const float* neps = (const float*)d_in[6];
  const float* tprev = (const float*)d_in[7];
  float* out = (float*)d_out;

  // Workspace layout (~68.5 MB, same as validated baseline)
  float* h = (float*)d_ws;
  float* nlogit = h + (size_t)B_TOK * HID;
  float* ewbuf = nlogit + (size_t)B_TOK * NE;
  float* partials = ewbuf + (size_t)B_TOK * NE;
  float* maskbuf = partials + (B_TOK / 8) * NE;

  dim3 g1(HID / BN, B_TOK / BM);  // 16 x 64
  k_gemm1_mfma<<<g1, 256, 0, stream>>>(x, W1, b1, h);
  k_noise<<<B_TOK / 8, 512, 0, stream>>>(x, nw, nlogit);
  k_gemm2_softmax<<<B_TOK / 8, 512, 0, stream>>>(h, W2, b2, neps, nlogit,
                                                 ewbuf, partials);
  k_mask<<<1, 64, 0, stream>>>(partials, tprev, maskbuf, B_TOK / 8);
  k_final<<<B_TOK / 4, 256, 0, stream>>>(ewbuf, maskbuf, out);
}

// Round 4
// 769.039 us; speedup vs baseline: 2.9215x; 1.4223x over previous
//
#include <hip/hip_runtime.h>
#include <hip/hip_bf16.h>
#include <math.h>

// Problem constants (fixed by the reference)
#define B_TOK 8192
#define IN_DIM 4096
#define HID 2048
#define NE 64
#define TOPK 8

typedef __attribute__((ext_vector_type(8))) _Float16 f16x8;
typedef __attribute__((ext_vector_type(4))) float f32x4;

// ---------------------------------------------------------------------------
// GEMM1: h = relu(x @ W1 + b1) via split-precision fp16 MFMA. (validated R3)
// 128x128 tile, BK=32, 4 waves (2x2), 4x4 16x16x32 frags/wave, XOR-swizzle.
// ---------------------------------------------------------------------------
#define BM 128
#define BN 128
#define BK 32

__global__ __launch_bounds__(256) void k_gemm1_mfma(
    const float* __restrict__ x, const float* __restrict__ W1,
    const float* __restrict__ b1, float* __restrict__ h) {
  __shared__ _Float16 AsH[BM * BK];
  __shared__ _Float16 AsL[BM * BK];
  __shared__ _Float16 BsH[BN * BK];
  __shared__ _Float16 BsL[BN * BK];

  const int tid = threadIdx.x;
  const int lane = tid & 63;
  const int w = tid >> 6;
  const int wr = (w >> 1) << 6;
  const int wc = (w & 1) << 6;
  const int row0 = blockIdx.y * BM;
  const int col0 = blockIdx.x * BN;

  const int fr = lane & 15;
  const int kg = lane >> 4;
  int aoff[4], boff[4];
#pragma unroll
  for (int m = 0; m < 4; ++m) {
    const int r = wr + m * 16 + fr;
    aoff[m] = r * BK + ((kg ^ ((r >> 1) & 3)) << 3);
  }
#pragma unroll
  for (int n = 0; n < 4; ++n) {
    const int c = wc + n * 16 + fr;
    boff[n] = c * BK + ((kg ^ ((c >> 1) & 3)) << 3);
  }

  f32x4 acc[4][4];
  const f32x4 zero = {0.f, 0.f, 0.f, 0.f};
#pragma unroll
  for (int m = 0; m < 4; ++m)
#pragma unroll
    for (int n = 0; n < 4; ++n) acc[m][n] = zero;

  for (int k0 = 0; k0 < IN_DIM; k0 += BK) {
    __syncthreads();
#pragma unroll
    for (int i = 0; i < 2; ++i) {
      const int ar = (tid >> 2) + i * 64;
      const int g = tid & 3;
      const float* src = &x[(size_t)(row0 + ar) * IN_DIM + k0 + (g << 3)];
      const float4 f0 = *(const float4*)src;
      const float4 f1 = *(const float4*)(src + 4);
      const float fv[8] = {f0.x, f0.y, f0.z, f0.w, f1.x, f1.y, f1.z, f1.w};
      f16x8 vh, vl;
#pragma unroll
      for (int j = 0; j < 8; ++j) {
        const _Float16 hi = (_Float16)fv[j];
        const float res = fv[j] - (float)hi;
        vh[j] = hi;
        vl[j] = (_Float16)res;
      }
      const int off = ar * BK + (((g ^ ((ar >> 1) & 3))) << 3);
      *(f16x8*)&AsH[off] = vh;
      *(f16x8*)&AsL[off] = vl;
    }
    {
      const int n = tid & 127;
      const int k16 = (tid >> 7) << 4;
      const float* src = &W1[(size_t)(k0 + k16) * HID + col0 + n];
      float fv[16];
#pragma unroll
      for (int j = 0; j < 16; ++j) fv[j] = src[(size_t)j * HID];
      f16x8 vh0, vl0, vh1, vl1;
#pragma unroll
      for (int j = 0; j < 8; ++j) {
        _Float16 hi = (_Float16)fv[j];
        float res = fv[j] - (float)hi;
        vh0[j] = hi;
        vl0[j] = (_Float16)res;
        hi = (_Float16)fv[j + 8];
        res = fv[j + 8] - (float)hi;
        vh1[j] = hi;
        vl1[j] = (_Float16)res;
      }
      const int g0 = k16 >> 3;
      const int sw = (n >> 1) & 3;
      *(f16x8*)&BsH[n * BK + ((g0 ^ sw) << 3)] = vh0;
      *(f16x8*)&BsL[n * BK + ((g0 ^ sw) << 3)] = vl0;
      *(f16x8*)&BsH[n * BK + (((g0 + 1) ^ sw) << 3)] = vh1;
      *(f16x8*)&BsL[n * BK + (((g0 + 1) ^ sw) << 3)] = vl1;
    }
    __syncthreads();
    f16x8 aH[4], bH[4], bL[4], aL[4];
#pragma unroll
    for (int m = 0; m < 4; ++m) aH[m] = *(const f16x8*)&AsH[aoff[m]];
#pragma unroll
    for (int n = 0; n < 4; ++n) bH[n] = *(const f16x8*)&BsH[boff[n]];
#pragma unroll
    for (int m = 0; m < 4; ++m)
#pragma unroll
      for (int n = 0; n < 4; ++n)
        acc[m][n] = __builtin_amdgcn_mfma_f32_16x16x32_f16(aH[m], bH[n],
                                                           acc[m][n], 0, 0, 0);
#pragma unroll
    for (int n = 0; n < 4; ++n) bL[n] = *(const f16x8*)&BsL[boff[n]];
#pragma unroll
    for (int m = 0; m < 4; ++m)
#pragma unroll
      for (int n = 0; n < 4; ++n)
        acc[m][n] = __builtin_amdgcn_mfma_f32_16x16x32_f16(aH[m], bL[n],
                                                           acc[m][n], 0, 0, 0);
#pragma unroll
    for (int m = 0; m < 4; ++m) aL[m] = *(const f16x8*)&AsL[aoff[m]];
#pragma unroll
    for (int m = 0; m < 4; ++m)
#pragma unroll
      for (int n = 0; n < 4; ++n)
        acc[m][n] = __builtin_amdgcn_mfma_f32_16x16x32_f16(aL[m], bH[n],
                                                           acc[m][n], 0, 0, 0);
  }
  const int crow = (lane >> 4) << 2;
  const int ccol = lane & 15;
#pragma unroll
  for (int n = 0; n < 4; ++n) {
    const int gc = col0 + wc + n * 16 + ccol;
    const float bias = b1[gc];
#pragma unroll
    for (int m = 0; m < 4; ++m) {
      const int gr = row0 + wr + m * 16 + crow;
#pragma unroll
      for (int j = 0; j < 4; ++j)
        h[(size_t)(gr + j) * HID + gc] = fmaxf(acc[m][n][j] + bias, 0.f);
    }
  }
}

// ---------------------------------------------------------------------------
// Prep: split W2 [2048,64] and nw [4096,64] into fp16 hi/lo, transposed to
// [col][k] so B-fragments are single 16B loads. Blocks 0-63: W2 col;
// blocks 64-127: nw col. (Tiny, L2-bound, ~5 us.)
// ---------------------------------------------------------------------------
__global__ __launch_bounds__(256) void k_prep_w(
    const float* __restrict__ W2, const float* __restrict__ nw,
    _Float16* __restrict__ w2h, _Float16* __restrict__ w2l,
    _Float16* __restrict__ nwh, _Float16* __restrict__ nwl) {
  const int b = blockIdx.x;
  if (b < NE) {
    const int c = b;
    for (int k = threadIdx.x; k < HID; k += 256) {
      const float v = W2[(size_t)k * NE + c];
      const _Float16 hi = (_Float16)v;
      w2h[(size_t)c * HID + k] = hi;
      w2l[(size_t)c * HID + k] = (_Float16)(v - (float)hi);
    }
  } else {
    const int c = b - NE;
    for (int k = threadIdx.x; k < IN_DIM; k += 256) {
      const float v = nw[(size_t)k * NE + c];
      const _Float16 hi = (_Float16)v;
      nwh[(size_t)c * IN_DIM + k] = hi;
      nwl[(size_t)c * IN_DIM + k] = (_Float16)(v - (float)hi);
    }
  }
}

// ---------------------------------------------------------------------------
// Fused tail: noise = x@nw ; logits = h@W2 + b2 + neps*noise ; softmax ;
// per-block column partial sums. fp16x3 MFMA, A read directly from global
// (fp32 -> split in-register; no LDS, no reuse to exploit, no barriers).
// Wave = 16 rows x 64 cols (1 m-frag x 4 n-frags) -> softmax is wave-local
// (row lives in 16 lanes x 4 regs). Block = 4 waves = 64 rows; grid = 128.
// ---------------------------------------------------------------------------
__global__ __launch_bounds__(256) void k_tail(
    const float* __restrict__ x, const float* __restrict__ h,
    const _Float16* __restrict__ w2h, const _Float16* __restrict__ w2l,
    const _Float16* __restrict__ nwh, const _Float16* __restrict__ nwl,
    const float* __restrict__ b2, const float* __restrict__ neps,
    float* __restrict__ ew, float* __restrict__ partials) {
  __shared__ float psum[4][NE];
  const int tid = threadIdx.x;
  const int lane = tid & 63;
  const int w = tid >> 6;
  const int r0 = blockIdx.x * 64 + w * 16;  // wave's 16-row strip
  const int fr = lane & 15;                 // A row / B col within frag
  const int kg = lane >> 4;                 // k-group

  f32x4 acc[4], accn[4];
  const f32x4 zero = {0.f, 0.f, 0.f, 0.f};
#pragma unroll
  for (int n = 0; n < 4; ++n) {
    acc[n] = zero;
    accn[n] = zero;
  }

  // ---- noise loop: x @ nwT, K = 4096 ----
  {
    const float* xrow = &x[(size_t)(r0 + fr) * IN_DIM + (kg << 3)];
    for (int k0 = 0; k0 < IN_DIM; k0 += 32) {
      const float4 f0 = *(const float4*)&xrow[k0];
      const float4 f1 = *(const float4*)&xrow[k0 + 4];
      const float fv[8] = {f0.x, f0.y, f0.z, f0.w, f1.x, f1.y, f1.z, f1.w};
      f16x8 ah, al;
#pragma unroll
      for (int j = 0; j < 8; ++j) {
        const _Float16 hi = (_Float16)fv[j];
        ah[j] = hi;
        al[j] = (_Float16)(fv[j] - (float)hi);
      }
#pragma unroll
      for (int n = 0; n < 4; ++n) {
        const size_t boffs = (size_t)(n * 16 + fr) * IN_DIM + k0 + (kg << 3);
        const f16x8 bh = *(const f16x8*)&nwh[boffs];
        const f16x8 bl = *(const f16x8*)&nwl[boffs];
        accn[n] = __builtin_amdgcn_mfma_f32_16x16x32_f16(ah, bh, accn[n], 0, 0, 0);
        accn[n] = __builtin_amdgcn_mfma_f32_16x16x32_f16(al, bh, accn[n], 0, 0, 0);
        accn[n] = __builtin_amdgcn_mfma_f32_16x16x32_f16(ah, bl, accn[n], 0, 0, 0);
      }
    }
  }

  // ---- main loop: h @ w2T, K = 2048 ----
  {
    const float* hrow = &h[(size_t)(r0 + fr) * HID + (kg << 3)];
    for (int k0 = 0; k0 < HID; k0 += 32) {
      const float4 f0 = *(const float4*)&hrow[k0];
      const float4 f1 = *(const float4*)&hrow[k0 + 4];
      const float fv[8] = {f0.x, f0.y, f0.z, f0.w, f1.x, f1.y, f1.z, f1.w};
      f16x8 ah, al;
#pragma unroll
      for (int j = 0; j < 8; ++j) {
        const _Float16 hi = (_Float16)fv[j];
        ah[j] = hi;
        al[j] = (_Float16)(fv[j] - (float)hi);
      }
#pragma unroll
      for (int n = 0; n < 4; ++n) {
        const size_t boffs = (size_t)(n * 16 + fr) * HID + k0 + (kg << 3);
        const f16x8 bh = *(const f16x8*)&w2h[boffs];
        const f16x8 bl = *(const f16x8*)&w2l[boffs];
        acc[n] = __builtin_amdgcn_mfma_f32_16x16x32_f16(ah, bh, acc[n], 0, 0, 0);
        acc[n] = __builtin_amdgcn_mfma_f32_16x16x32_f16(al, bh, acc[n], 0, 0, 0);
        acc[n] = __builtin_amdgcn_mfma_f32_16x16x32_f16(ah, bl, acc[n], 0, 0, 0);
      }
    }
  }

  // ---- logits: + b2 + neps * noise.  C layout: row=kg*4+j, col=n*16+fr ----
#pragma unroll
  for (int n = 0; n < 4; ++n) {
    const float bias = b2[n * 16 + fr];
#pragma unroll
    for (int j = 0; j < 4; ++j) {
      const int row = r0 + (kg << 2) + j;
      acc[n][j] += bias + neps[(size_t)row * NE + n * 16 + fr] * accn[n][j];
    }
  }

  // ---- row softmax (row = 16 lanes x 4 regs) + column partials ----
  float colpart[4] = {0.f, 0.f, 0.f, 0.f};
#pragma unroll
  for (int j = 0; j < 4; ++j) {
    float m = fmaxf(fmaxf(acc[0][j], acc[1][j]), fmaxf(acc[2][j], acc[3][j]));
#pragma unroll
    for (int o = 8; o > 0; o >>= 1) m = fmaxf(m, __shfl_xor(m, o));
    float e[4];
    float s = 0.f;
#pragma unroll
    for (int n = 0; n < 4; ++n) {
      e[n] = __expf(acc[n][j] - m);
      s += e[n];
    }
#pragma unroll
    for (int o = 8; o > 0; o >>= 1) s += __shfl_xor(s, o);
    const int row = r0 + (kg << 2) + j;
#pragma unroll
    for (int n = 0; n < 4; ++n) {
      const float p = e[n] / s;
      ew[(size_t)row * NE + n * 16 + fr] = p;
      colpart[n] += p;
    }
  }
#pragma unroll
  for (int n = 0; n < 4; ++n) {
    colpart[n] += __shfl_xor(colpart[n], 16);
    colpart[n] += __shfl_xor(colpart[n], 32);
  }
  if (lane < 16) {
#pragma unroll
    for (int n = 0; n < 4; ++n) psum[w][n * 16 + lane] = colpart[n];
  }
  __syncthreads();
  if (tid < NE) {
    partials[(size_t)blockIdx.x * NE + tid] =
        psum[0][tid] + psum[1][tid] + psum[2][tid] + psum[3][tid];
  }
}

// ---------------------------------------------------------------------------
// mask from running totals (single block, deterministic)
// ---------------------------------------------------------------------------
__global__ void k_mask(const float* __restrict__ partials,
                       const float* __restrict__ total_prev,
                       float* __restrict__ maskbuf, int nblocks) {
  const int e = threadIdx.x;
  float t = total_prev[e];
  for (int b = 0; b < nblocks; ++b) t += partials[b * NE + e];
  float s = t;
#pragma unroll
  for (int o = 32; o > 0; o >>= 1) s += __shfl_xor(s, o);
  const float mean = s * (1.f / 64.f);
  maskbuf[e] = (t - mean > 0.f) ? 0.f : 1.f;
}

// ---------------------------------------------------------------------------
// mask + top-8 (ties keep larger index) + renormalizing softmax
// ---------------------------------------------------------------------------
__global__ __launch_bounds__(256) void k_final(
    const float* __restrict__ ew, const float* __restrict__ maskbuf,
    float* __restrict__ out) {
  const int tid = threadIdx.x;
  const int lane = tid & 63;
  const int row = (blockIdx.x << 2) + (tid >> 6);
  const float v = ew[row * NE + lane] * maskbuf[lane];
  int rank = 0;
#pragma unroll
  for (int j = 0; j < 64; ++j) {
    const float vj = __shfl(v, j);
    rank += (vj > v) || (vj == v && j > lane);
  }
  const bool keep = rank < TOPK;
  float m = keep ? v : -INFINITY;
#pragma unroll
  for (int o = 32; o > 0; o >>= 1) m = fmaxf(m, __shfl_xor(m, o));
  const float e = keep ? __expf(v - m) : 0.f;
  float s = e;
#pragma unroll
  for (int o = 32; o > 0; o >>= 1) s += __shfl_xor(s, o);
  out[row * NE + lane] = e / s;
}

// ---------------------------------------------------------------------------
extern "C" void kernel_launch(void* const* d_in, const int* in_sizes, int n_in,
                              void* d_out, int out_size, void* d_ws,
                              size_t ws_size, hipStream_t stream) {
  const float* x = (const float*)d_in[0];
  const float* W1 = (const float*)d_in[1];
  const float* b1 = (const float*)d_in[2];
  const float* W2 = (const float*)d_in[3];
  const float* b2 = (const float*)d_in[4];
  const float* nw = (const float*)d_in[5];
  const float* neps = (const float*)d_in[6];
  const float* tprev = (const float*)d_in[7];
  float* out = (float*)d_out;

  // Workspace layout (~67.6 MB; previously-validated footprint was 68.5 MB)
  float* h = (float*)d_ws;                             // 8192*2048 f32 = 64 MB
  _Float16* w2h = (_Float16*)(h + (size_t)B_TOK * HID);  // 64*2048 f16
  _Float16* w2l = w2h + (size_t)NE * HID;
  _Float16* nwh = w2l + (size_t)NE * HID;                // 64*4096 f16
  _Float16* nwl = nwh + (size_t)NE * IN_DIM;
  float* ewbuf = (float*)(nwl + (size_t)NE * IN_DIM);    // 8192*64 f32 = 2 MB
  float* partials = ewbuf + (size_t)B_TOK * NE;          // 128*64
  float* maskbuf = partials + 128 * NE;                  // 64

  k_prep_w<<<128, 256, 0, stream>>>(W2, nw, w2h, w2l, nwh, nwl);
  dim3 g1(HID / BN, B_TOK / BM);  // 16 x 64
  k_gemm1_mfma<<<g1, 256, 0, stream>>>(x, W1, b1, h);
  k_tail<<<B_TOK / 64, 256, 0, stream>>>(x, h, w2h, w2l, nwh, nwl, b2, neps,
                                         ewbuf, partials);
  k_mask<<<1, 64, 0, stream>>>(partials, tprev, maskbuf, B_TOK / 64);
  k_final<<<B_TOK / 4, 256, 0, stream>>>(ewbuf, maskbuf, out);
}

// Round 5
// 575.345 us; speedup vs baseline: 3.9051x; 1.3367x over previous
//
#include <hip/hip_runtime.h>
#include <hip/hip_bf16.h>
#include <math.h>

// Problem constants (fixed by the reference)
#define B_TOK 8192
#define IN_DIM 4096
#define HID 2048
#define NE 64
#define TOPK 8

typedef __attribute__((ext_vector_type(8))) _Float16 f16x8;
typedef __attribute__((ext_vector_type(4))) float f32x4;

#define AS1 __attribute__((address_space(1)))
#define AS3 __attribute__((address_space(3)))

#define BM 128
#define BN 128
#define BK 32

// ---------------------------------------------------------------------------
// Prep: split W2 [2048,64] and nw [4096,64] into fp16 hi/lo, transposed to
// [col][k]. Blocks 0-63: W2 col; blocks 64-127: nw col.
// ---------------------------------------------------------------------------
__global__ __launch_bounds__(256) void k_prep_w(
    const float* __restrict__ W2, const float* __restrict__ nw,
    _Float16* __restrict__ w2h, _Float16* __restrict__ w2l,
    _Float16* __restrict__ nwh, _Float16* __restrict__ nwl) {
  const int b = blockIdx.x;
  if (b < NE) {
    const int c = b;
    for (int k = threadIdx.x; k < HID; k += 256) {
      const float v = W2[(size_t)k * NE + c];
      const _Float16 hi = (_Float16)v;
      w2h[(size_t)c * HID + k] = hi;
      w2l[(size_t)c * HID + k] = (_Float16)(v - (float)hi);
    }
  } else {
    const int c = b - NE;
    for (int k = threadIdx.x; k < IN_DIM; k += 256) {
      const float v = nw[(size_t)k * NE + c];
      const _Float16 hi = (_Float16)v;
      nwh[(size_t)c * IN_DIM + k] = hi;
      nwl[(size_t)c * IN_DIM + k] = (_Float16)(v - (float)hi);
    }
  }
}

// ---------------------------------------------------------------------------
// Prep: build the W1 LDS image — split fp16 hi/lo, tiled per (colblk c of
// 128, ktile of 32) and XOR-swizzled EXACTLY like the BsH/BsL LDS layout:
//   img[(c*128 + kt)*4096 + n*32 + ((g ^ sw(n))<<3) + j]
//     = split(W1[kt*32 + g*8 + j][c*128 + n]),  sw(n) = (n>>1)&3.
// gemm1 then stages B with plain global_load_lds (linear dest == image).
// ---------------------------------------------------------------------------
__global__ __launch_bounds__(256) void k_prep_w1img(
    const float* __restrict__ W1, _Float16* __restrict__ imgH,
    _Float16* __restrict__ imgL) {
  const int c = blockIdx.x;   // 0..15
  const int kt = blockIdx.y;  // 0..127
  const int tid = threadIdx.x;
  const int n = tid & 127;
  const int g0 = tid >> 7;  // 0..1
  const size_t base = ((size_t)c * (IN_DIM / 32) + kt) * 4096;
  const int sw = (n >> 1) & 3;
#pragma unroll
  for (int gi = 0; gi < 2; ++gi) {
    const int g = g0 * 2 + gi;  // 0..3
    const float* src = &W1[(size_t)(kt * 32 + g * 8) * HID + c * 128 + n];
    f16x8 vh, vl;
#pragma unroll
    for (int j = 0; j < 8; ++j) {
      const float v = src[(size_t)j * HID];
      const _Float16 hi = (_Float16)v;
      vh[j] = hi;
      vl[j] = (_Float16)(v - (float)hi);
    }
    const size_t off = base + n * 32 + ((g ^ sw) << 3);
    *(f16x8*)&imgH[off] = vh;
    *(f16x8*)&imgL[off] = vl;
  }
}

// ---------------------------------------------------------------------------
// GEMM1 (fast): h = relu(x @ W1 + b1), fp16x3 split MFMA.
// B staged via global_load_lds from the pre-split swizzled W1 image
// (zero conversion VALU, zero ds_writes for B). A staged with in-register
// fp32->f16 split as before. 128x128 tile, BK=32, 4 waves (2x2), 4x4 frags.
// ---------------------------------------------------------------------------
__global__ __launch_bounds__(256) void k_gemm1_img(
    const float* __restrict__ x, const _Float16* __restrict__ w1ih,
    const _Float16* __restrict__ w1il, const float* __restrict__ b1,
    float* __restrict__ h) {
  __shared__ _Float16 AsH[BM * BK];
  __shared__ _Float16 AsL[BM * BK];
  __shared__ _Float16 BsH[BN * BK];
  __shared__ _Float16 BsL[BN * BK];

  const int tid = threadIdx.x;
  const int lane = tid & 63;
  const int w = tid >> 6;
  const int wr = (w >> 1) << 6;
  const int wc = (w & 1) << 6;
  const int row0 = blockIdx.y * BM;

  const int fr = lane & 15;
  const int kg = lane >> 4;
  int aoff[4], boff[4];
#pragma unroll
  for (int m = 0; m < 4; ++m) {
    const int r = wr + m * 16 + fr;
    aoff[m] = r * BK + ((kg ^ ((r >> 1) & 3)) << 3);
  }
#pragma unroll
  for (int n = 0; n < 4; ++n) {
    const int c = wc + n * 16 + fr;
    boff[n] = c * BK + ((kg ^ ((c >> 1) & 3)) << 3);
  }

  f32x4 acc[4][4];
  const f32x4 zero = {0.f, 0.f, 0.f, 0.f};
#pragma unroll
  for (int m = 0; m < 4; ++m)
#pragma unroll
    for (int n = 0; n < 4; ++n) acc[m][n] = zero;

  for (int k0 = 0; k0 < IN_DIM; k0 += BK) {
    __syncthreads();
    // ---- stage B: 4x global_load_lds 16B from swizzled image (no VALU) ----
    {
      const size_t tb =
          (((size_t)blockIdx.x * (IN_DIM / 32) + (k0 >> 5)) * 4096) *
          sizeof(_Float16);
      const char* gh = (const char*)w1ih + tb + (lane << 4);
      const char* gl = (const char*)w1il + tb + (lane << 4);
#pragma unroll
      for (int i = 0; i < 2; ++i) {
        const int cb = ((w << 1) + i) << 10;  // 1 KiB chunk per wave-call
        __builtin_amdgcn_global_load_lds((const AS1 unsigned int*)(gh + cb),
                                         (AS3 unsigned int*)((char*)BsH + cb),
                                         16, 0, 0);
        __builtin_amdgcn_global_load_lds((const AS1 unsigned int*)(gl + cb),
                                         (AS3 unsigned int*)((char*)BsL + cb),
                                         16, 0, 0);
      }
    }
    // ---- stage A: 128 rows x 32 k, fp32 -> f16 hi/lo in-register ----
#pragma unroll
    for (int i = 0; i < 2; ++i) {
      const int ar = (tid >> 2) + i * 64;
      const int g = tid & 3;
      const float* src = &x[(size_t)(row0 + ar) * IN_DIM + k0 + (g << 3)];
      const float4 f0 = *(const float4*)src;
      const float4 f1 = *(const float4*)(src + 4);
      const float fv[8] = {f0.x, f0.y, f0.z, f0.w, f1.x, f1.y, f1.z, f1.w};
      f16x8 vh, vl;
#pragma unroll
      for (int j = 0; j < 8; ++j) {
        const _Float16 hi = (_Float16)fv[j];
        vh[j] = hi;
        vl[j] = (_Float16)(fv[j] - (float)hi);
      }
      const int off = ar * BK + (((g ^ ((ar >> 1) & 3))) << 3);
      *(f16x8*)&AsH[off] = vh;
      *(f16x8*)&AsL[off] = vl;
    }
    __syncthreads();
    // ---- fragments + 48 MFMA (hi*hi, hi*lo, lo*hi) ----
    f16x8 aH[4], bH[4], bL[4], aL[4];
#pragma unroll
    for (int m = 0; m < 4; ++m) aH[m] = *(const f16x8*)&AsH[aoff[m]];
#pragma unroll
    for (int n = 0; n < 4; ++n) bH[n] = *(const f16x8*)&BsH[boff[n]];
#pragma unroll
    for (int m = 0; m < 4; ++m)
#pragma unroll
      for (int n = 0; n < 4; ++n)
        acc[m][n] = __builtin_amdgcn_mfma_f32_16x16x32_f16(aH[m], bH[n],
                                                           acc[m][n], 0, 0, 0);
#pragma unroll
    for (int n = 0; n < 4; ++n) bL[n] = *(const f16x8*)&BsL[boff[n]];
#pragma unroll
    for (int m = 0; m < 4; ++m)
#pragma unroll
      for (int n = 0; n < 4; ++n)
        acc[m][n] = __builtin_amdgcn_mfma_f32_16x16x32_f16(aH[m], bL[n],
                                                           acc[m][n], 0, 0, 0);
#pragma unroll
    for (int m = 0; m < 4; ++m) aL[m] = *(const f16x8*)&AsL[aoff[m]];
#pragma unroll
    for (int m = 0; m < 4; ++m)
#pragma unroll
      for (int n = 0; n < 4; ++n)
        acc[m][n] = __builtin_amdgcn_mfma_f32_16x16x32_f16(aL[m], bH[n],
                                                           acc[m][n], 0, 0, 0);
  }
  const int crow = (lane >> 4) << 2;
  const int ccol = lane & 15;
  const int col0 = blockIdx.x * BN;
#pragma unroll
  for (int n = 0; n < 4; ++n) {
    const int gc = col0 + wc + n * 16 + ccol;
    const float bias = b1[gc];
#pragma unroll
    for (int m = 0; m < 4; ++m) {
      const int gr = row0 + wr + m * 16 + crow;
#pragma unroll
      for (int j = 0; j < 4; ++j)
        h[(size_t)(gr + j) * HID + gc] = fmaxf(acc[m][n][j] + bias, 0.f);
    }
  }
}

// ---------------------------------------------------------------------------
// GEMM1 (fallback, R4-proven): in-kernel W1 fp32 load + split.
// ---------------------------------------------------------------------------
__global__ __launch_bounds__(256) void k_gemm1_v1(
    const float* __restrict__ x, const float* __restrict__ W1,
    const float* __restrict__ b1, float* __restrict__ h) {
  __shared__ _Float16 AsH[BM * BK];
  __shared__ _Float16 AsL[BM * BK];
  __shared__ _Float16 BsH[BN * BK];
  __shared__ _Float16 BsL[BN * BK];

  const int tid = threadIdx.x;
  const int lane = tid & 63;
  const int w = tid >> 6;
  const int wr = (w >> 1) << 6;
  const int wc = (w & 1) << 6;
  const int row0 = blockIdx.y * BM;
  const int col0 = blockIdx.x * BN;

  const int fr = lane & 15;
  const int kg = lane >> 4;
  int aoff[4], boff[4];
#pragma unroll
  for (int m = 0; m < 4; ++m) {
    const int r = wr + m * 16 + fr;
    aoff[m] = r * BK + ((kg ^ ((r >> 1) & 3)) << 3);
  }
#pragma unroll
  for (int n = 0; n < 4; ++n) {
    const int c = wc + n * 16 + fr;
    boff[n] = c * BK + ((kg ^ ((c >> 1) & 3)) << 3);
  }

  f32x4 acc[4][4];
  const f32x4 zero = {0.f, 0.f, 0.f, 0.f};
#pragma unroll
  for (int m = 0; m < 4; ++m)
#pragma unroll
    for (int n = 0; n < 4; ++n) acc[m][n] = zero;

  for (int k0 = 0; k0 < IN_DIM; k0 += BK) {
    __syncthreads();
#pragma unroll
    for (int i = 0; i < 2; ++i) {
      const int ar = (tid >> 2) + i * 64;
      const int g = tid & 3;
      const float* src = &x[(size_t)(row0 + ar) * IN_DIM + k0 + (g << 3)];
      const float4 f0 = *(const float4*)src;
      const float4 f1 = *(const float4*)(src + 4);
      const float fv[8] = {f0.x, f0.y, f0.z, f0.w, f1.x, f1.y, f1.z, f1.w};
      f16x8 vh, vl;
#pragma unroll
      for (int j = 0; j < 8; ++j) {
        const _Float16 hi = (_Float16)fv[j];
        vh[j] = hi;
        vl[j] = (_Float16)(fv[j] - (float)hi);
      }
      const int off = ar * BK + (((g ^ ((ar >> 1) & 3))) << 3);
      *(f16x8*)&AsH[off] = vh;
      *(f16x8*)&AsL[off] = vl;
    }
    {
      const int n = tid & 127;
      const int k16 = (tid >> 7) << 4;
      const float* src = &W1[(size_t)(k0 + k16) * HID + col0 + n];
      float fv[16];
#pragma unroll
      for (int j = 0; j < 16; ++j) fv[j] = src[(size_t)j * HID];
      f16x8 vh0, vl0, vh1, vl1;
#pragma unroll
      for (int j = 0; j < 8; ++j) {
        _Float16 hi = (_Float16)fv[j];
        vh0[j] = hi;
        vl0[j] = (_Float16)(fv[j] - (float)hi);
        hi = (_Float16)fv[j + 8];
        vh1[j] = hi;
        vl1[j] = (_Float16)(fv[j + 8] - (float)hi);
      }
      const int g0 = k16 >> 3;
      const int sw = (n >> 1) & 3;
      *(f16x8*)&BsH[n * BK + ((g0 ^ sw) << 3)] = vh0;
      *(f16x8*)&BsL[n * BK + ((g0 ^ sw) << 3)] = vl0;
      *(f16x8*)&BsH[n * BK + (((g0 + 1) ^ sw) << 3)] = vh1;
      *(f16x8*)&BsL[n * BK + (((g0 + 1) ^ sw) << 3)] = vl1;
    }
    __syncthreads();
    f16x8 aH[4], bH[4], bL[4], aL[4];
#pragma unroll
    for (int m = 0; m < 4; ++m) aH[m] = *(const f16x8*)&AsH[aoff[m]];
#pragma unroll
    for (int n = 0; n < 4; ++n) bH[n] = *(const f16x8*)&BsH[boff[n]];
#pragma unroll
    for (int m = 0; m < 4; ++m)
#pragma unroll
      for (int n = 0; n < 4; ++n)
        acc[m][n] = __builtin_amdgcn_mfma_f32_16x16x32_f16(aH[m], bH[n],
                                                           acc[m][n], 0, 0, 0);
#pragma unroll
    for (int n = 0; n < 4; ++n) bL[n] = *(const f16x8*)&BsL[boff[n]];
#pragma unroll
    for (int m = 0; m < 4; ++m)
#pragma unroll
      for (int n = 0; n < 4; ++n)
        acc[m][n] = __builtin_amdgcn_mfma_f32_16x16x32_f16(aH[m], bL[n],
                                                           acc[m][n], 0, 0, 0);
#pragma unroll
    for (int m = 0; m < 4; ++m) aL[m] = *(const f16x8*)&AsL[aoff[m]];
#pragma unroll
    for (int m = 0; m < 4; ++m)
#pragma unroll
      for (int n = 0; n < 4; ++n)
        acc[m][n] = __builtin_amdgcn_mfma_f32_16x16x32_f16(aL[m], bH[n],
                                                           acc[m][n], 0, 0, 0);
  }
  const int crow = (lane >> 4) << 2;
  const int ccol = lane & 15;
#pragma unroll
  for (int n = 0; n < 4; ++n) {
    const int gc = col0 + wc + n * 16 + ccol;
    const float bias = b1[gc];
#pragma unroll
    for (int m = 0; m < 4; ++m) {
      const int gr = row0 + wr + m * 16 + crow;
#pragma unroll
      for (int j = 0; j < 4; ++j)
        h[(size_t)(gr + j) * HID + gc] = fmaxf(acc[m][n][j] + bias, 0.f);
    }
  }
}

// ---------------------------------------------------------------------------
// Tail GEMM (fast): K-split x4 for occupancy. Block = 4 waves x 16 rows;
// grid = (128 row-strips, 4 k-chunks) = 512 blocks = 2048 waves (8/CU).
// Each block computes its K-chunk of noise = x@nwT and main = h@w2T and
// writes partial accumulators to ws.
// ---------------------------------------------------------------------------
__global__ __launch_bounds__(256) void k_tail_gemm(
    const float* __restrict__ x, const float* __restrict__ h,
    const _Float16* __restrict__ w2h, const _Float16* __restrict__ w2l,
    const _Float16* __restrict__ nwh, const _Float16* __restrict__ nwl,
    float* __restrict__ partsN, float* __restrict__ partsM) {
  const int tid = threadIdx.x;
  const int lane = tid & 63;
  const int w = tid >> 6;
  const int kc = blockIdx.y;  // 0..3
  const int r0 = blockIdx.x * 64 + w * 16;
  const int fr = lane & 15;
  const int kg = lane >> 4;

  f32x4 acc[4], accn[4];
  const f32x4 zero = {0.f, 0.f, 0.f, 0.f};
#pragma unroll
  for (int n = 0; n < 4; ++n) {
    acc[n] = zero;
    accn[n] = zero;
  }

  // ---- noise chunk: K in [kc*1024, kc*1024+1024) ----
  {
    const int kb = kc * 1024;
    const float* xrow = &x[(size_t)(r0 + fr) * IN_DIM + kb + (kg << 3)];
    for (int k0 = 0; k0 < 1024; k0 += 32) {
      const float4 f0 = *(const float4*)&xrow[k0];
      const float4 f1 = *(const float4*)&xrow[k0 + 4];
      const float fv[8] = {f0.x, f0.y, f0.z, f0.w, f1.x, f1.y, f1.z, f1.w};
      f16x8 ah, al;
#pragma unroll
      for (int j = 0; j < 8; ++j) {
        const _Float16 hi = (_Float16)fv[j];
        ah[j] = hi;
        al[j] = (_Float16)(fv[j] - (float)hi);
      }
#pragma unroll
      for (int n = 0; n < 4; ++n) {
        const size_t boffs =
            (size_t)(n * 16 + fr) * IN_DIM + kb + k0 + (kg << 3);
        const f16x8 bh = *(const f16x8*)&nwh[boffs];
        const f16x8 bl = *(const f16x8*)&nwl[boffs];
        accn[n] =
            __builtin_amdgcn_mfma_f32_16x16x32_f16(ah, bh, accn[n], 0, 0, 0);
        accn[n] =
            __builtin_amdgcn_mfma_f32_16x16x32_f16(al, bh, accn[n], 0, 0, 0);
        accn[n] =
            __builtin_amdgcn_mfma_f32_16x16x32_f16(ah, bl, accn[n], 0, 0, 0);
      }
    }
  }

  // ---- main chunk: K in [kc*512, kc*512+512) ----
  {
    const int kb = kc * 512;
    const float* hrow = &h[(size_t)(r0 + fr) * HID + kb + (kg << 3)];
    for (int k0 = 0; k0 < 512; k0 += 32) {
      const float4 f0 = *(const float4*)&hrow[k0];
      const float4 f1 = *(const float4*)&hrow[k0 + 4];
      const float fv[8] = {f0.x, f0.y, f0.z, f0.w, f1.x, f1.y, f1.z, f1.w};
      f16x8 ah, al;
#pragma unroll
      for (int j = 0; j < 8; ++j) {
        const _Float16 hi = (_Float16)fv[j];
        ah[j] = hi;
        al[j] = (_Float16)(fv[j] - (float)hi);
      }
#pragma unroll
      for (int n = 0; n < 4; ++n) {
        const size_t boffs = (size_t)(n * 16 + fr) * HID + kb + k0 + (kg << 3);
        const f16x8 bh = *(const f16x8*)&w2h[boffs];
        const f16x8 bl = *(const f16x8*)&w2l[boffs];
        acc[n] = __builtin_amdgcn_mfma_f32_16x16x32_f16(ah, bh, acc[n], 0, 0, 0);
        acc[n] = __builtin_amdgcn_mfma_f32_16x16x32_f16(al, bh, acc[n], 0, 0, 0);
        acc[n] = __builtin_amdgcn_mfma_f32_16x16x32_f16(ah, bl, acc[n], 0, 0, 0);
      }
    }
  }

  // ---- write partials. C layout: row = kg*4+j, col = n*16+fr ----
#pragma unroll
  for (int n = 0; n < 4; ++n) {
#pragma unroll
    for (int j = 0; j < 4; ++j) {
      const int row = r0 + (kg << 2) + j;
      const int col = n * 16 + fr;
      partsN[((size_t)kc * B_TOK + row) * NE + col] = accn[n][j];
      partsM[((size_t)kc * B_TOK + row) * NE + col] = acc[n][j];
    }
  }
}

// ---------------------------------------------------------------------------
// Tail finish (fast): sum k-chunks, logits, softmax, ew + column partials.
// Same lane->element mapping as k_tail_gemm. Grid = 128 blocks x 4 waves.
// ---------------------------------------------------------------------------
__global__ __launch_bounds__(256) void k_tail_fin(
    const float* __restrict__ partsN, const float* __restrict__ partsM,
    const float* __restrict__ b2, const float* __restrict__ neps,
    float* __restrict__ ew, float* __restrict__ partials) {
  __shared__ float psum[4][NE];
  const int tid = threadIdx.x;
  const int lane = tid & 63;
  const int w = tid >> 6;
  const int r0 = blockIdx.x * 64 + w * 16;
  const int fr = lane & 15;
  const int kg = lane >> 4;

  f32x4 acc[4];
#pragma unroll
  for (int n = 0; n < 4; ++n) {
#pragma unroll
    for (int j = 0; j < 4; ++j) {
      const int row = r0 + (kg << 2) + j;
      const int col = n * 16 + fr;
      float nz = 0.f, a = 0.f;
#pragma unroll
      for (int kc = 0; kc < 4; ++kc) {
        nz += partsN[((size_t)kc * B_TOK + row) * NE + col];
        a += partsM[((size_t)kc * B_TOK + row) * NE + col];
      }
      acc[n][j] = a + b2[col] + neps[(size_t)row * NE + col] * nz;
    }
  }

  // ---- row softmax (row = 16 lanes x 4 regs) + column partials ----
  float colpart[4] = {0.f, 0.f, 0.f, 0.f};
#pragma unroll
  for (int j = 0; j < 4; ++j) {
    float m = fmaxf(fmaxf(acc[0][j], acc[1][j]), fmaxf(acc[2][j], acc[3][j]));
#pragma unroll
    for (int o = 8; o > 0; o >>= 1) m = fmaxf(m, __shfl_xor(m, o));
    float e[4];
    float s = 0.f;
#pragma unroll
    for (int n = 0; n < 4; ++n) {
      e[n] = __expf(acc[n][j] - m);
      s += e[n];
    }
#pragma unroll
    for (int o = 8; o > 0; o >>= 1) s += __shfl_xor(s, o);
    const int row = r0 + (kg << 2) + j;
#pragma unroll
    for (int n = 0; n < 4; ++n) {
      const float p = e[n] / s;
      ew[(size_t)row * NE + n * 16 + fr] = p;
      colpart[n] += p;
    }
  }
#pragma unroll
  for (int n = 0; n < 4; ++n) {
    colpart[n] += __shfl_xor(colpart[n], 16);
    colpart[n] += __shfl_xor(colpart[n], 32);
  }
  if (lane < 16) {
#pragma unroll
    for (int n = 0; n < 4; ++n) psum[w][n * 16 + lane] = colpart[n];
  }
  __syncthreads();
  if (tid < NE) {
    partials[(size_t)blockIdx.x * NE + tid] =
        psum[0][tid] + psum[1][tid] + psum[2][tid] + psum[3][tid];
  }
}

// ---------------------------------------------------------------------------
// Tail (fallback, R4-proven): single-pass fused noise+main+softmax.
// ---------------------------------------------------------------------------
__global__ __launch_bounds__(256) void k_tail_v1(
    const float* __restrict__ x, const float* __restrict__ h,
    const _Float16* __restrict__ w2h, const _Float16* __restrict__ w2l,
    const _Float16* __restrict__ nwh, const _Float16* __restrict__ nwl,
    const float* __restrict__ b2, const float* __restrict__ neps,
    float* __restrict__ ew, float* __restrict__ partials) {
  __shared__ float psum[4][NE];
  const int tid = threadIdx.x;
  const int lane = tid & 63;
  const int w = tid >> 6;
  const int r0 = blockIdx.x * 64 + w * 16;
  const int fr = lane & 15;
  const int kg = lane >> 4;

  f32x4 acc[4], accn[4];
  const f32x4 zero = {0.f, 0.f, 0.f, 0.f};
#pragma unroll
  for (int n = 0; n < 4; ++n) {
    acc[n] = zero;
    accn[n] = zero;
  }
  {
    const float* xrow = &x[(size_t)(r0 + fr) * IN_DIM + (kg << 3)];
    for (int k0 = 0; k0 < IN_DIM; k0 += 32) {
      const float4 f0 = *(const float4*)&xrow[k0];
      const float4 f1 = *(const float4*)&xrow[k0 + 4];
      const float fv[8] = {f0.x, f0.y, f0.z, f0.w, f1.x, f1.y, f1.z, f1.w};
      f16x8 ah, al;
#pragma unroll
      for (int j = 0; j < 8; ++j) {
        const _Float16 hi = (_Float16)fv[j];
        ah[j] = hi;
        al[j] = (_Float16)(fv[j] - (float)hi);
      }
#pragma unroll
      for (int n = 0; n < 4; ++n) {
        const size_t boffs = (size_t)(n * 16 + fr) * IN_DIM + k0 + (kg << 3);
        const f16x8 bh = *(const f16x8*)&nwh[boffs];
        const f16x8 bl = *(const f16x8*)&nwl[boffs];
        accn[n] =
            __builtin_amdgcn_mfma_f32_16x16x32_f16(ah, bh, accn[n], 0, 0, 0);
        accn[n] =
            __builtin_amdgcn_mfma_f32_16x16x32_f16(al, bh, accn[n], 0, 0, 0);
        accn[n] =
            __builtin_amdgcn_mfma_f32_16x16x32_f16(ah, bl, accn[n], 0, 0, 0);
      }
    }
  }
  {
    const float* hrow = &h[(size_t)(r0 + fr) * HID + (kg << 3)];
    for (int k0 = 0; k0 < HID; k0 += 32) {
      const float4 f0 = *(const float4*)&hrow[k0];
      const float4 f1 = *(const float4*)&hrow[k0 + 4];
      const float fv[8] = {f0.x, f0.y, f0.z, f0.w, f1.x, f1.y, f1.z, f1.w};
      f16x8 ah, al;
#pragma unroll
      for (int j = 0; j < 8; ++j) {
        const _Float16 hi = (_Float16)fv[j];
        ah[j] = hi;
        al[j] = (_Float16)(fv[j] - (float)hi);
      }
#pragma unroll
      for (int n = 0; n < 4; ++n) {
        const size_t boffs = (size_t)(n * 16 + fr) * HID + k0 + (kg << 3);
        const f16x8 bh = *(const f16x8*)&w2h[boffs];
        const f16x8 bl = *(const f16x8*)&w2l[boffs];
        acc[n] = __builtin_amdgcn_mfma_f32_16x16x32_f16(ah, bh, acc[n], 0, 0, 0);
        acc[n] = __builtin_amdgcn_mfma_f32_16x16x32_f16(al, bh, acc[n], 0, 0, 0);
        acc[n] = __builtin_amdgcn_mfma_f32_16x16x32_f16(ah, bl, acc[n], 0, 0, 0);
      }
    }
  }
#pragma unroll
  for (int n = 0; n < 4; ++n) {
    const float bias = b2[n * 16 + fr];
#pragma unroll
    for (int j = 0; j < 4; ++j) {
      const int row = r0 + (kg << 2) + j;
      acc[n][j] += bias + neps[(size_t)row * NE + n * 16 + fr] * accn[n][j];
    }
  }
  float colpart[4] = {0.f, 0.f, 0.f, 0.f};
#pragma unroll
  for (int j = 0; j < 4; ++j) {
    float m = fmaxf(fmaxf(acc[0][j], acc[1][j]), fmaxf(acc[2][j], acc[3][j]));
#pragma unroll
    for (int o = 8; o > 0; o >>= 1) m = fmaxf(m, __shfl_xor(m, o));
    float e[4];
    float s = 0.f;
#pragma unroll
    for (int n = 0; n < 4; ++n) {
      e[n] = __expf(acc[n][j] - m);
      s += e[n];
    }
#pragma unroll
    for (int o = 8; o > 0; o >>= 1) s += __shfl_xor(s, o);
    const int row = r0 + (kg << 2) + j;
#pragma unroll
    for (int n = 0; n < 4; ++n) {
      const float p = e[n] / s;
      ew[(size_t)row * NE + n * 16 + fr] = p;
      colpart[n] += p;
    }
  }
#pragma unroll
  for (int n = 0; n < 4; ++n) {
    colpart[n] += __shfl_xor(colpart[n], 16);
    colpart[n] += __shfl_xor(colpart[n], 32);
  }
  if (lane < 16) {
#pragma unroll
    for (int n = 0; n < 4; ++n) psum[w][n * 16 + lane] = colpart[n];
  }
  __syncthreads();
  if (tid < NE) {
    partials[(size_t)blockIdx.x * NE + tid] =
        psum[0][tid] + psum[1][tid] + psum[2][tid] + psum[3][tid];
  }
}

// ---------------------------------------------------------------------------
// mask from running totals (single block, deterministic)
// ---------------------------------------------------------------------------
__global__ void k_mask(const float* __restrict__ partials,
                       const float* __restrict__ total_prev,
                       float* __restrict__ maskbuf, int nblocks) {
  const int e = threadIdx.x;
  float t = total_prev[e];
  for (int b = 0; b < nblocks; ++b) t += partials[b * NE + e];
  float s = t;
#pragma unroll
  for (int o = 32; o > 0; o >>= 1) s += __shfl_xor(s, o);
  const float mean = s * (1.f / 64.f);
  maskbuf[e] = (t - mean > 0.f) ? 0.f : 1.f;
}

// ---------------------------------------------------------------------------
// mask + top-8 (ties keep larger index) + renormalizing softmax
// ---------------------------------------------------------------------------
__global__ __launch_bounds__(256) void k_final(
    const float* __restrict__ ew, const float* __restrict__ maskbuf,
    float* __restrict__ out) {
  const int tid = threadIdx.x;
  const int lane = tid & 63;
  const int row = (blockIdx.x << 2) + (tid >> 6);
  const float v = ew[row * NE + lane] * maskbuf[lane];
  int rank = 0;
#pragma unroll
  for (int j = 0; j < 64; ++j) {
    const float vj = __shfl(v, j);
    rank += (vj > v) || (vj == v && j > lane);
  }
  const bool keep = rank < TOPK;
  float m = keep ? v : -INFINITY;
#pragma unroll
  for (int o = 32; o > 0; o >>= 1) m = fmaxf(m, __shfl_xor(m, o));
  const float e = keep ? __expf(v - m) : 0.f;
  float s = e;
#pragma unroll
  for (int o = 32; o > 0; o >>= 1) s += __shfl_xor(s, o);
  out[row * NE + lane] = e / s;
}

// ---------------------------------------------------------------------------
extern "C" void kernel_launch(void* const* d_in, const int* in_sizes, int n_in,
                              void* d_out, int out_size, void* d_ws,
                              size_t ws_size, hipStream_t stream) {
  const float* x = (const float*)d_in[0];
  const float* W1 = (const float*)d_in[1];
  const float* b1 = (const float*)d_in[2];
  const float* W2 = (const float*)d_in[3];
  const float* b2 = (const float*)d_in[4];
  const float* nw = (const float*)d_in[5];
  const float* neps = (const float*)d_in[6];
  const float* tprev = (const float*)d_in[7];
  float* out = (float*)d_out;

  char* ws = (char*)d_ws;
  const size_t sz_h = (size_t)B_TOK * HID * 4;       // 64 MB
  const size_t sz_img = (size_t)HID * IN_DIM * 2;    // 16 MB each
  const size_t sz_parts = (size_t)4 * B_TOK * NE * 4;  // 8 MB each
  const size_t sz_w2s = (size_t)NE * HID * 2;
  const size_t sz_nws = (size_t)NE * IN_DIM * 2;
  const size_t sz_ew = (size_t)B_TOK * NE * 4;
  const size_t need_fast = sz_h + 2 * sz_img + 2 * sz_parts + 2 * sz_w2s +
                           2 * sz_nws + sz_ew + 128 * NE * 4 + 256;

  if (ws_size >= need_fast) {
    // ---- fast path: W1 image + gload_lds GEMM1, K-split tail ----
    float* h = (float*)ws;
    _Float16* w1ih = (_Float16*)(ws + sz_h);
    _Float16* w1il = (_Float16*)(ws + sz_h + sz_img);
    float* partsN = (float*)(ws + sz_h + 2 * sz_img);
    float* partsM = (float*)(ws + sz_h + 2 * sz_img + sz_parts);
    _Float16* w2h = (_Float16*)(ws + sz_h + 2 * sz_img + 2 * sz_parts);
    _Float16* w2l = w2h + (size_t)NE * HID;
    _Float16* nwh = w2l + (size_t)NE * HID;
    _Float16* nwl = nwh + (size_t)NE * IN_DIM;
    float* ewbuf = (float*)(nwl + (size_t)NE * IN_DIM);
    float* partials = ewbuf + (size_t)B_TOK * NE;
    float* maskbuf = partials + 128 * NE;

    k_prep_w<<<128, 256, 0, stream>>>(W2, nw, w2h, w2l, nwh, nwl);
    k_prep_w1img<<<dim3(HID / BN, IN_DIM / BK), 256, 0, stream>>>(W1, w1ih,
                                                                  w1il);
    k_gemm1_img<<<dim3(HID / BN, B_TOK / BM), 256, 0, stream>>>(x, w1ih, w1il,
                                                                b1, h);
    k_tail_gemm<<<dim3(B_TOK / 64, 4), 256, 0, stream>>>(x, h, w2h, w2l, nwh,
                                                         nwl, partsN, partsM);
    k_tail_fin<<<B_TOK / 64, 256, 0, stream>>>(partsN, partsM, b2, neps, ewbuf,
                                               partials);
    k_mask<<<1, 64, 0, stream>>>(partials, tprev, maskbuf, B_TOK / 64);
    k_final<<<B_TOK / 4, 256, 0, stream>>>(ewbuf, maskbuf, out);
  } else {
    // ---- fallback: R4-proven path (67.6 MB ws) ----
    float* h = (float*)ws;
    _Float16* w2h = (_Float16*)(h + (size_t)B_TOK * HID);
    _Float16* w2l = w2h + (size_t)NE * HID;
    _Float16* nwh = w2l + (size_t)NE * HID;
    _Float16* nwl = nwh + (size_t)NE * IN_DIM;
    float* ewbuf = (float*)(nwl + (size_t)NE * IN_DIM);
    float* partials = ewbuf + (size_t)B_TOK * NE;
    float* maskbuf = partials + 128 * NE;

    k_prep_w<<<128, 256, 0, stream>>>(W2, nw, w2h, w2l, nwh, nwl);
    k_gemm1_v1<<<dim3(HID / BN, B_TOK / BM), 256, 0, stream>>>(x, W1, b1, h);
    k_tail_v1<<<B_TOK / 64, 256, 0, stream>>>(x, h, w2h, w2l, nwh, nwl, b2,
                                              neps, ewbuf, partials);
    k_mask<<<1, 64, 0, stream>>>(partials, tprev, maskbuf, B_TOK / 64);
    k_final<<<B_TOK / 4, 256, 0, stream>>>(ewbuf, maskbuf, out);
  }
}